// Round 1
// baseline (113.264 us; speedup 1.0000x reference)
//
#include <hip/hip_runtime.h>

// BSplineKAN: out[b,c] = sum_i cp[c,i] * N_{i,3}(clip(x[b,c], -0.99, 0.99))
// Knots: 12 uniform knots on [-1,1], h = 2/11, NOT clamped -> every in-range
// basis function is a translate of the cardinal cubic B-spline. For
// x in [t_j, t_{j+1}), u = (x - t_j)/h:
//   N_{j-3} = (1-u)^3/6, N_{j-2} = (3u^3-6u^2+4)/6,
//   N_{j-1} = (-3u^3+3u^2+3u+1)/6, N_j = u^3/6
// Out-of-range i (i<0 or i>7) are simply dropped (match reference's truncated
// Cox-de Boor). Fold cp into per-(channel, interval) cubic coefficients:
//   P_{c,j}(u) = a0 + a1*u + a2*u^2 + a3*u^3
// Table: 64 channels x 11 intervals x float4 = 11264 B in LDS.

constexpr int CH  = 64;   // channels
constexpr int PCP = 8;    // control points per channel
constexpr int NJ  = 11;   // intervals
constexpr int TBL = CH * NJ;  // 704 float4 entries

__global__ __launch_bounds__(256) void bspline_kan_kernel(
    const float* __restrict__ x,
    const float* __restrict__ cp,
    float* __restrict__ out,
    int n4)
{
    __shared__ float4 tbl[TBL];

    // Build the per-(channel, interval) cubic coefficient table.
    for (int t = threadIdx.x; t < TBL; t += 256) {
        int c = t / NJ;
        int j = t - c * NJ;
        float p[4];
#pragma unroll
        for (int r = 0; r < 4; ++r) {
            int i = j - 3 + r;
            p[r] = (i >= 0 && i < PCP) ? cp[c * PCP + i] : 0.0f;
        }
        float4 a;
        a.x = (p[0] + 4.0f * p[1] + p[2]) * (1.0f / 6.0f);
        a.y = (p[2] - p[0]) * 0.5f;
        a.z = (p[0] - 2.0f * p[1] + p[2]) * 0.5f;
        a.w = (p[3] - p[0] + 3.0f * (p[1] - p[2])) * (1.0f / 6.0f);
        tbl[t] = a;
    }
    __syncthreads();

    const float inv_h = 5.5f;  // 1 / (2/11), maps [-1,1] -> [0,11]

    int idx    = blockIdx.x * blockDim.x + threadIdx.x;
    int stride = gridDim.x * blockDim.x;
    const float4* __restrict__ x4 = (const float4*)x;
    float4* __restrict__ o4 = (float4*)out;

    for (int i = idx; i < n4; i += stride) {
        float4 xv = x4[i];
        // 4 consecutive elements = 4 consecutive channels (C=64, 4 | 64).
        // base_c is loop-invariant since stride*4 % 64 == 0.
        int base_c = (i << 2) & (CH - 1);
        float xs[4] = {xv.x, xv.y, xv.z, xv.w};
        float r[4];
#pragma unroll
        for (int e = 0; e < 4; ++e) {
            float xx = fminf(fmaxf(xs[e], -0.99f), 0.99f);
            float fz = (xx + 1.0f) * inv_h;          // in [0.055, 10.945]
            float fj = floorf(fz);
            int j = (int)fj;
            j = max(0, min(j, NJ - 1));
            float u = fz - (float)j;                 // local coordinate in [0,1)
            float4 a = tbl[(base_c + e) * NJ + j];
            r[e] = fmaf(fmaf(fmaf(a.w, u, a.z), u, a.y), u, a.x);
        }
        float4 ov = {r[0], r[1], r[2], r[3]};
        o4[i] = ov;
    }
}

extern "C" void kernel_launch(void* const* d_in, const int* in_sizes, int n_in,
                              void* d_out, int out_size, void* d_ws, size_t ws_size,
                              hipStream_t stream) {
    const float* x  = (const float*)d_in[0];   // [262144, 64] fp32
    const float* cp = (const float*)d_in[1];   // [64, 8] fp32
    float* out = (float*)d_out;                // [262144, 64] fp32

    int n4 = in_sizes[0] / 4;                  // 4194304 float4s
    // 2048 blocks = 8 blocks/CU on 256 CUs; 8 grid-stride iters/thread
    // amortizes the LDS table build.
    bspline_kan_kernel<<<2048, 256, 0, stream>>>(x, cp, out, n4);
}